// Round 1
// baseline (84931.531 us; speedup 1.0000x reference)
//
#include <hip/hip_runtime.h>
#include <hip/hip_cooperative_groups.h>

namespace cg = cooperative_groups;

constexpr int N    = 4096;
constexpr int T    = 2048;
constexpr int NBLK = 256;                       // one WG per CU
constexpr int NTHR = 256;                       // 4 waves
constexpr int WAVES = NTHR / 64;                // 4
constexpr int ROWS_PER_WG   = N / NBLK;         // 16
constexpr int ROWS_PER_WAVE = ROWS_PER_WG / WAVES; // 4

struct Params {
    const float *x_in, *w, *E_L, *C_m, *G, *R_I, *f_v, *f_I, *dts, *b_s,
                *a_v, *b_v, *tinf, *dV, *I_A, *v0, *ts0, *tv0, *ia0;
    float *out;     // [2, T, N]
    float *ia_buf;  // double buffer: 2*N floats in d_ws
};

__global__ __launch_bounds__(NTHR, 1)
void glif_persistent(Params p)
{
    cg::grid_group grid = cg::this_grid();
    __shared__ float ia_lds[N];                 // 16 KB: full I_add vector

    const int tid  = threadIdx.x;
    const int wg   = blockIdx.x;
    const int wave = tid >> 6;
    const int lane = tid & 63;
    const int row_base = wg * ROWS_PER_WG + wave * ROWS_PER_WAVE;
    const int myrow    = row_base + lane;       // valid only for lane < ROWS_PER_WAVE

    // ---- per-neuron state + params live in registers of lanes 0..3 of each wave
    float v = 0.f, ts = 0.f, tv = 0.f;
    float c_EL = 0.f, c_Cm = 1.f, c_G = 0.f, c_RI = 0.f, c_fv = 0.f, c_fI = 0.f,
          c_dts = 0.f, c_bs = 0.f, c_av = 0.f, c_bv = 0.f, c_tinf = 0.f,
          c_dV = 0.f, c_IA = 0.f;
    if (lane < ROWS_PER_WAVE) {
        v  = p.v0[myrow];  ts = p.ts0[myrow];  tv = p.tv0[myrow];
        c_EL = p.E_L[myrow];  c_Cm = p.C_m[myrow];  c_G  = p.G[myrow];
        c_RI = p.R_I[myrow];  c_fv = p.f_v[myrow];  c_fI = p.f_I[myrow];
        c_dts = p.dts[myrow]; c_bs = p.b_s[myrow];  c_av = p.a_v[myrow];
        c_bv  = p.b_v[myrow]; c_tinf = p.tinf[myrow];
        c_dV  = p.dV[myrow];  c_IA = p.I_A[myrow];
    }

    // ---- init I_add buffer 0 from I_add0 (deterministic every call)
    for (int i = wg * NTHR + tid; i < N; i += NBLK * NTHR)
        p.ia_buf[i] = p.ia0[i];
    grid.sync();

    const float4* wrow0 = (const float4*)(p.w + (size_t)(row_base + 0) * N);
    const float4* wrow1 = (const float4*)(p.w + (size_t)(row_base + 1) * N);
    const float4* wrow2 = (const float4*)(p.w + (size_t)(row_base + 2) * N);
    const float4* wrow3 = (const float4*)(p.w + (size_t)(row_base + 3) * N);
    const float4* lds4  = (const float4*)ia_lds;

    for (int t = 0; t < T; ++t) {
        const float* src = p.ia_buf + (size_t)(t & 1) * N;
        float*       dst = p.ia_buf + (size_t)((t + 1) & 1) * N;

        // ---- stage I_add into LDS (whole vector, coalesced float4)
        for (int i = tid; i < N / 4; i += NTHR)
            ((float4*)ia_lds)[i] = ((const float4*)src)[i];
        __syncthreads();

        // ---- matvec: each wave does 4 rows, lanes stride columns by float4
        float a0 = 0.f, a1 = 0.f, a2 = 0.f, a3 = 0.f;
        #pragma unroll 4
        for (int k = 0; k < N / 256; ++k) {     // 16 iterations
            const int idx = lane + 64 * k;
            float4 ia = lds4[idx];
            float4 r0 = wrow0[idx];
            float4 r1 = wrow1[idx];
            float4 r2 = wrow2[idx];
            float4 r3 = wrow3[idx];
            a0 += r0.x * ia.x + r0.y * ia.y + r0.z * ia.z + r0.w * ia.w;
            a1 += r1.x * ia.x + r1.y * ia.y + r1.z * ia.z + r1.w * ia.w;
            a2 += r2.x * ia.x + r2.y * ia.y + r2.z * ia.z + r2.w * ia.w;
            a3 += r3.x * ia.x + r3.y * ia.y + r3.z * ia.z + r3.w * ia.w;
        }
        // ---- 64-lane butterfly reduction for all 4 row sums
        #pragma unroll
        for (int m = 32; m >= 1; m >>= 1) {
            a0 += __shfl_xor(a0, m, 64);
            a1 += __shfl_xor(a1, m, 64);
            a2 += __shfl_xor(a2, m, 64);
            a3 += __shfl_xor(a3, m, 64);
        }

        // ---- neuron update: lanes 0..3 own rows row_base+0..3
        if (lane < ROWS_PER_WAVE) {
            float y = a0;
            if (lane == 1) y = a1;
            if (lane == 2) y = a2;
            if (lane == 3) y = a3;

            float I      = p.x_in[(size_t)t * N + myrow] + y;
            float dv     = (I * c_RI - c_G * (v - c_EL)) / c_Cm;
            float v_next = v + dv;
            float thr    = ts + tv;
            float ssoft  = 1.f / (1.f + expf(thr - v_next));   // sigmoid(v_next - thr)
            bool  sp     = (v_next >= thr);
            float v_reset = c_EL + c_fv * (v - c_EL) - c_dV;
            float v_new  = sp ? v_reset : v_next;
            float ts_new = (1.f - c_bs) * ts + (sp ? c_dts : 0.f);
            float dtv    = c_av * (v_new - c_EL) - c_bv * (tv - c_tinf);
            float tv_new = tv + (sp ? 0.f : dtv);
            float ia_new = (1.f - c_fI) * ia_lds[myrow] + ssoft * c_IA;

            v = v_new; ts = ts_new; tv = tv_new;

            p.out[(size_t)t * N + myrow] = v_new;
            p.out[(size_t)T * N + (size_t)t * N + myrow] = ssoft;
            dst[myrow] = ia_new;
        }

        // one grid-wide barrier per step: publishes dst, and guards the LDS
        // buffer against next-iteration overwrite (includes block-level sync).
        grid.sync();
    }
}

extern "C" void kernel_launch(void* const* d_in, const int* in_sizes, int n_in,
                              void* d_out, int out_size, void* d_ws, size_t ws_size,
                              hipStream_t stream)
{
    Params p;
    p.x_in = (const float*)d_in[0];
    p.w    = (const float*)d_in[1];
    p.E_L  = (const float*)d_in[2];
    p.C_m  = (const float*)d_in[3];
    p.G    = (const float*)d_in[4];
    p.R_I  = (const float*)d_in[5];
    p.f_v  = (const float*)d_in[6];
    p.f_I  = (const float*)d_in[7];
    p.dts  = (const float*)d_in[8];
    p.b_s  = (const float*)d_in[9];
    p.a_v  = (const float*)d_in[10];
    p.b_v  = (const float*)d_in[11];
    p.tinf = (const float*)d_in[12];
    p.dV   = (const float*)d_in[13];
    p.I_A  = (const float*)d_in[14];
    p.v0   = (const float*)d_in[15];
    p.ts0  = (const float*)d_in[16];
    p.tv0  = (const float*)d_in[17];
    p.ia0  = (const float*)d_in[18];
    p.out  = (float*)d_out;
    p.ia_buf = (float*)d_ws;   // needs 2*N*4 = 32 KB

    void* args[] = { &p };
    hipLaunchCooperativeKernel((const void*)glif_persistent,
                               dim3(NBLK), dim3(NTHR), args, 0, stream);
}

// Round 2
// 62378.394 us; speedup vs baseline: 1.3616x; 1.3616x over previous
//
#include <hip/hip_runtime.h>
#include <hip/hip_cooperative_groups.h>

namespace cg = cooperative_groups;

constexpr int N    = 4096;
constexpr int T    = 2048;
constexpr int NBLK = 256;                       // one WG per CU
constexpr int NTHR = 512;                       // 8 waves
constexpr int WAVES = NTHR / 64;                // 8
constexpr int ROWS_PER_WG   = N / NBLK;         // 16
constexpr int ROWS_PER_WAVE = ROWS_PER_WG / WAVES; // 2

struct Params {
    const float *x_in, *w, *E_L, *C_m, *G, *R_I, *f_v, *f_I, *dts, *b_s,
                *a_v, *b_v, *tinf, *dV, *I_A, *v0, *ts0, *tv0, *ia0;
    float *out;     // [2, T, N]
    float *ia_buf;  // double buffer: 2*N floats in d_ws
};

__global__ __launch_bounds__(NTHR, 2)
void glif_persistent(Params p)
{
    cg::grid_group grid = cg::this_grid();
    __shared__ float ia_lds[N];                 // 16 KB: full I_add vector

    const int tid  = threadIdx.x;
    const int wg   = blockIdx.x;
    const int wave = tid >> 6;
    const int lane = tid & 63;
    const int row0 = wg * ROWS_PER_WG + wave * ROWS_PER_WAVE;   // this wave's 2 rows
    const int myrow = row0 + lane;              // valid only for lane < 2

    // ---- per-neuron state + params live in registers of lanes 0..1 of each wave
    float v = 0.f, ts = 0.f, tv = 0.f;
    float c_EL = 0.f, c_Cm = 1.f, c_G = 0.f, c_RI = 0.f, c_fv = 0.f, c_fI = 0.f,
          c_dts = 0.f, c_bs = 0.f, c_av = 0.f, c_bv = 0.f, c_tinf = 0.f,
          c_dV = 0.f, c_IA = 0.f;
    if (lane < ROWS_PER_WAVE) {
        v  = p.v0[myrow];  ts = p.ts0[myrow];  tv = p.tv0[myrow];
        c_EL = p.E_L[myrow];  c_Cm = p.C_m[myrow];  c_G  = p.G[myrow];
        c_RI = p.R_I[myrow];  c_fv = p.f_v[myrow];  c_fI = p.f_I[myrow];
        c_dts = p.dts[myrow]; c_bs = p.b_s[myrow];  c_av = p.a_v[myrow];
        c_bv  = p.b_v[myrow]; c_tinf = p.tinf[myrow];
        c_dV  = p.dV[myrow];  c_IA = p.I_A[myrow];
    }

    // ---- load this wave's two w rows into registers, permanently.
    // 2 rows x 16 float4 = 128 VGPRs/lane. All indices compile-time constant.
    const float4* wrowA = (const float4*)(p.w + (size_t)(row0 + 0) * N);
    const float4* wrowB = (const float4*)(p.w + (size_t)(row0 + 1) * N);
    float4 wA[16], wB[16];
    #pragma unroll
    for (int k = 0; k < 16; ++k) {
        wA[k] = wrowA[lane + 64 * k];
        wB[k] = wrowB[lane + 64 * k];
    }

    // ---- init I_add buffer 0 from I_add0 (deterministic every call)
    for (int i = wg * NTHR + tid; i < N; i += NBLK * NTHR)
        p.ia_buf[i] = p.ia0[i];
    grid.sync();

    const float4* lds4 = (const float4*)ia_lds;

    for (int t = 0; t < T; ++t) {
        const float* src = p.ia_buf + (size_t)(t & 1) * N;
        float*       dst = p.ia_buf + (size_t)((t + 1) & 1) * N;

        // ---- stage I_add into LDS (1024 float4, 512 threads -> 2 each)
        ((float4*)ia_lds)[tid]        = ((const float4*)src)[tid];
        ((float4*)ia_lds)[tid + NTHR] = ((const float4*)src)[tid + NTHR];
        __syncthreads();

        // ---- matvec from register-resident w: 2 rows/wave
        float a0 = 0.f, a1 = 0.f;
        #pragma unroll
        for (int k = 0; k < 16; ++k) {
            float4 ia = lds4[lane + 64 * k];
            a0 += wA[k].x * ia.x + wA[k].y * ia.y + wA[k].z * ia.z + wA[k].w * ia.w;
            a1 += wB[k].x * ia.x + wB[k].y * ia.y + wB[k].z * ia.z + wB[k].w * ia.w;
        }
        // ---- 64-lane butterfly reduction for both row sums
        #pragma unroll
        for (int m = 32; m >= 1; m >>= 1) {
            a0 += __shfl_xor(a0, m, 64);
            a1 += __shfl_xor(a1, m, 64);
        }

        // ---- neuron update: lane 0 -> row0, lane 1 -> row0+1
        if (lane < ROWS_PER_WAVE) {
            float y = (lane == 0) ? a0 : a1;

            float I      = p.x_in[(size_t)t * N + myrow] + y;
            float dv     = (I * c_RI - c_G * (v - c_EL)) / c_Cm;
            float v_next = v + dv;
            float thr    = ts + tv;
            float ssoft  = 1.f / (1.f + expf(thr - v_next));   // sigmoid(v_next - thr)
            bool  sp     = (v_next >= thr);
            float v_reset = c_EL + c_fv * (v - c_EL) - c_dV;
            float v_new  = sp ? v_reset : v_next;
            float ts_new = (1.f - c_bs) * ts + (sp ? c_dts : 0.f);
            float dtv    = c_av * (v_new - c_EL) - c_bv * (tv - c_tinf);
            float tv_new = tv + (sp ? 0.f : dtv);
            float ia_new = (1.f - c_fI) * ia_lds[myrow] + ssoft * c_IA;

            v = v_new; ts = ts_new; tv = tv_new;

            p.out[(size_t)t * N + myrow] = v_new;
            p.out[(size_t)T * N + (size_t)t * N + myrow] = ssoft;
            dst[myrow] = ia_new;
        }

        // one grid-wide barrier per step: publishes dst; also implies the
        // block-level sync that protects ia_lds from next-step overwrite.
        grid.sync();
    }
}

extern "C" void kernel_launch(void* const* d_in, const int* in_sizes, int n_in,
                              void* d_out, int out_size, void* d_ws, size_t ws_size,
                              hipStream_t stream)
{
    Params p;
    p.x_in = (const float*)d_in[0];
    p.w    = (const float*)d_in[1];
    p.E_L  = (const float*)d_in[2];
    p.C_m  = (const float*)d_in[3];
    p.G    = (const float*)d_in[4];
    p.R_I  = (const float*)d_in[5];
    p.f_v  = (const float*)d_in[6];
    p.f_I  = (const float*)d_in[7];
    p.dts  = (const float*)d_in[8];
    p.b_s  = (const float*)d_in[9];
    p.a_v  = (const float*)d_in[10];
    p.b_v  = (const float*)d_in[11];
    p.tinf = (const float*)d_in[12];
    p.dV   = (const float*)d_in[13];
    p.I_A  = (const float*)d_in[14];
    p.v0   = (const float*)d_in[15];
    p.ts0  = (const float*)d_in[16];
    p.tv0  = (const float*)d_in[17];
    p.ia0  = (const float*)d_in[18];
    p.out  = (float*)d_out;
    p.ia_buf = (float*)d_ws;   // needs 2*N*4 = 32 KB

    void* args[] = { &p };
    hipLaunchCooperativeKernel((const void*)glif_persistent,
                               dim3(NBLK), dim3(NTHR), args, 0, stream);
}

// Round 3
// 43899.850 us; speedup vs baseline: 1.9347x; 1.4209x over previous
//
#include <hip/hip_runtime.h>
#include <hip/hip_cooperative_groups.h>

namespace cg = cooperative_groups;

constexpr int N    = 4096;
constexpr int T    = 2048;
constexpr int NBLK = 256;                 // one WG per CU
constexpr int NTHR = 1024;                // 16 waves
constexpr int ROWS_PER_WG = N / NBLK;     // 16 -> 1 row per wave

struct Params {
    const float *x_in, *w, *E_L, *C_m, *G, *R_I, *f_v, *f_I, *dts, *b_s,
                *a_v, *b_v, *tinf, *dV, *I_A, *v0, *ts0, *tv0, *ia0;
    float *out;          // [2, T, N]
    unsigned *cnt;       // barrier counter (d_ws + 0)
    float *ia_buf;       // double buffer: 2*N floats (d_ws + 1024B)
};

#define DOT(wv, iv) ((wv).x*(iv).x + (wv).y*(iv).y + (wv).z*(iv).z + (wv).w*(iv).w)

__global__ __launch_bounds__(NTHR, 4)
void glif_persistent(Params p)
{
    cg::grid_group grid = cg::this_grid();
    __shared__ float ia_lds[N];           // 16 KB

    const int tid  = threadIdx.x;
    const int wg   = blockIdx.x;
    const int wave = tid >> 6;
    const int lane = tid & 63;
    const int row  = wg * ROWS_PER_WG + wave;   // wave-uniform: this wave's neuron

    // ---- wave-uniform params -> scalar loads (SGPRs)
    const float c_EL = p.E_L[row],  c_Cm = p.C_m[row], c_G   = p.G[row];
    const float c_RI = p.R_I[row],  c_fv = p.f_v[row], c_fI  = p.f_I[row];
    const float c_dts = p.dts[row], c_bs = p.b_s[row], c_av  = p.a_v[row];
    const float c_bv  = p.b_v[row], c_tinf = p.tinf[row];
    const float c_dV  = p.dV[row],  c_IA = p.I_A[row];

    // ---- per-neuron state (wave-uniform values, kept in regs)
    float v  = p.v0[row], ts = p.ts0[row], tv = p.tv0[row];
    float ia = p.ia0[row];                // this wave OWNS I_add[row]

    // ---- this wave's w row, permanently in 16 named float4 regs (64 VGPR)
    const float4* wr = (const float4*)(p.w + (size_t)row * N);
    const float4 w0  = wr[lane +   0], w1  = wr[lane +  64], w2  = wr[lane + 128],
                 w3  = wr[lane + 192], w4  = wr[lane + 256], w5  = wr[lane + 320],
                 w6  = wr[lane + 384], w7  = wr[lane + 448], w8  = wr[lane + 512],
                 w9  = wr[lane + 576], w10 = wr[lane + 640], w11 = wr[lane + 704],
                 w12 = wr[lane + 768], w13 = wr[lane + 832], w14 = wr[lane + 896],
                 w15 = wr[lane + 960];

    // ---- init: ia double-buffer slot 0 from ia0; zero barrier counter
    for (int i = wg * NTHR + tid; i < N; i += NBLK * NTHR)
        p.ia_buf[i] = p.ia0[i];
    if (wg == 0 && tid == 0) *p.cnt = 0u;
    grid.sync();                           // publishes init (CG sync fences)

    const float4* lds4 = (const float4*)ia_lds;

    for (int t = 0; t < T; ++t) {
        const float4* src = (const float4*)(p.ia_buf + (size_t)(t & 1) * N);
        float*        dst = p.ia_buf + (size_t)((t + 1) & 1) * N;

        // ---- stage I_add into LDS: 1024 float4, 1024 threads -> 1 each
        ((float4*)ia_lds)[tid] = src[tid];
        __syncthreads();

        // ---- matvec from register-resident w: 1 row/wave
        float a = 0.f;
        { float4 i0 = lds4[lane +   0]; a += DOT(w0 , i0); }
        { float4 i1 = lds4[lane +  64]; a += DOT(w1 , i1); }
        { float4 i2 = lds4[lane + 128]; a += DOT(w2 , i2); }
        { float4 i3 = lds4[lane + 192]; a += DOT(w3 , i3); }
        { float4 i4 = lds4[lane + 256]; a += DOT(w4 , i4); }
        { float4 i5 = lds4[lane + 320]; a += DOT(w5 , i5); }
        { float4 i6 = lds4[lane + 384]; a += DOT(w6 , i6); }
        { float4 i7 = lds4[lane + 448]; a += DOT(w7 , i7); }
        { float4 i8 = lds4[lane + 512]; a += DOT(w8 , i8); }
        { float4 i9 = lds4[lane + 576]; a += DOT(w9 , i9); }
        { float4 ia10 = lds4[lane + 640]; a += DOT(w10, ia10); }
        { float4 ia11 = lds4[lane + 704]; a += DOT(w11, ia11); }
        { float4 ia12 = lds4[lane + 768]; a += DOT(w12, ia12); }
        { float4 ia13 = lds4[lane + 832]; a += DOT(w13, ia13); }
        { float4 ia14 = lds4[lane + 896]; a += DOT(w14, ia14); }
        { float4 ia15 = lds4[lane + 960]; a += DOT(w15, ia15); }

        // ---- 64-lane butterfly: every lane ends with the full row sum
        #pragma unroll
        for (int m = 32; m >= 1; m >>= 1)
            a += __shfl_xor(a, m, 64);

        // ---- neuron update, computed redundantly by all 64 lanes (uniform)
        float x      = p.x_in[(size_t)t * N + row];       // uniform -> s_load
        float I      = x + a;
        float dv     = (I * c_RI - c_G * (v - c_EL)) / c_Cm;
        float v_next = v + dv;
        float thr    = ts + tv;
        float ssoft  = 1.f / (1.f + __expf(thr - v_next)); // sigmoid(v_next-thr)
        bool  sp     = (v_next >= thr);
        float v_reset = c_EL + c_fv * (v - c_EL) - c_dV;
        float v_new  = sp ? v_reset : v_next;
        float ts_new = (1.f - c_bs) * ts + (sp ? c_dts : 0.f);
        float dtv    = c_av * (v_new - c_EL) - c_bv * (tv - c_tinf);
        float tv_new = tv + (sp ? 0.f : dtv);
        float ia_new = (1.f - c_fI) * ia + ssoft * c_IA;

        v = v_new; ts = ts_new; tv = tv_new; ia = ia_new;

        if (lane == 0) {
            p.out[(size_t)t * N + row] = v_new;
            p.out[(size_t)T * N + (size_t)t * N + row] = ssoft;
            dst[row] = ia_new;
        }

        // ---- lightweight grid barrier: monotonic counter, leader-based
        __syncthreads();                   // all waves' dst stores issued
        if (tid == 0) {
            __threadfence();               // release: flush dst to device scope
            atomicAdd(p.cnt, 1u);
            const unsigned tgt = (unsigned)NBLK * (unsigned)(t + 1);
            while (__hip_atomic_load(p.cnt, __ATOMIC_RELAXED,
                                     __HIP_MEMORY_SCOPE_AGENT) < tgt)
                __builtin_amdgcn_s_sleep(1);
            __threadfence();               // acquire: invalidate stale caches
        }
        __syncthreads();                   // block proceeds; also guards ia_lds
    }
}

extern "C" void kernel_launch(void* const* d_in, const int* in_sizes, int n_in,
                              void* d_out, int out_size, void* d_ws, size_t ws_size,
                              hipStream_t stream)
{
    Params p;
    p.x_in = (const float*)d_in[0];
    p.w    = (const float*)d_in[1];
    p.E_L  = (const float*)d_in[2];
    p.C_m  = (const float*)d_in[3];
    p.G    = (const float*)d_in[4];
    p.R_I  = (const float*)d_in[5];
    p.f_v  = (const float*)d_in[6];
    p.f_I  = (const float*)d_in[7];
    p.dts  = (const float*)d_in[8];
    p.b_s  = (const float*)d_in[9];
    p.a_v  = (const float*)d_in[10];
    p.b_v  = (const float*)d_in[11];
    p.tinf = (const float*)d_in[12];
    p.dV   = (const float*)d_in[13];
    p.I_A  = (const float*)d_in[14];
    p.v0   = (const float*)d_in[15];
    p.ts0  = (const float*)d_in[16];
    p.tv0  = (const float*)d_in[17];
    p.ia0  = (const float*)d_in[18];
    p.out  = (float*)d_out;
    p.cnt    = (unsigned*)d_ws;                        // 4 B (padded to 1 KB)
    p.ia_buf = (float*)((char*)d_ws + 1024);           // 2*N*4 = 32 KB

    void* args[] = { &p };
    hipLaunchCooperativeKernel((const void*)glif_persistent,
                               dim3(NBLK), dim3(NTHR), args, 0, stream);
}

// Round 4
// 25526.128 us; speedup vs baseline: 3.3272x; 1.7198x over previous
//
#include <hip/hip_runtime.h>
#include <hip/hip_cooperative_groups.h>

namespace cg = cooperative_groups;

constexpr int N    = 4096;
constexpr int T    = 2048;
constexpr int NBLK = 256;                 // one WG per CU
constexpr int NTHR = 1024;                // 16 waves
constexpr int ROWS_PER_WG = N / NBLK;     // 16 -> 1 row per wave
constexpr int SLOT_STRIDE = 16;           // 16 uints = 64 B per flag slot

struct Params {
    const float *x_in, *w, *E_L, *C_m, *G, *R_I, *f_v, *f_I, *dts, *b_s,
                *a_v, *b_v, *tinf, *dV, *I_A, *v0, *ts0, *tv0, *ia0;
    float *out;          // [2, T, N]
    unsigned *flags;     // 256 slots x 64 B   (d_ws + 0)
    float *ia_buf;       // double buffer 2*N  (d_ws + 16 KB)
};

#define DOT(wv, iv) ((wv).x*(iv).x + (wv).y*(iv).y + (wv).z*(iv).z + (wv).w*(iv).w)

__global__ __launch_bounds__(NTHR, 4)
void glif_persistent(Params p)
{
    cg::grid_group grid = cg::this_grid();
    __shared__ float ia_lds[N];           // 16 KB

    const int tid  = threadIdx.x;
    const int wg   = blockIdx.x;
    const int wave = tid >> 6;
    const int lane = tid & 63;
    const int row  = wg * ROWS_PER_WG + wave;   // wave-uniform neuron index

    // ---- wave-uniform params (scalarized by compiler)
    const float c_EL = p.E_L[row],  c_Cm = p.C_m[row], c_G   = p.G[row];
    const float c_RI = p.R_I[row],  c_fv = p.f_v[row], c_fI  = p.f_I[row];
    const float c_dts = p.dts[row], c_bs = p.b_s[row], c_av  = p.a_v[row];
    const float c_bv  = p.b_v[row], c_tinf = p.tinf[row];
    const float c_dV  = p.dV[row],  c_IA = p.I_A[row];

    float v  = p.v0[row], ts = p.ts0[row], tv = p.tv0[row];
    float ia = p.ia0[row];                // this wave OWNS I_add[row]

    // ---- this wave's w row in 16 named float4 regs (AGPR/VGPR resident)
    const float4* wr = (const float4*)(p.w + (size_t)row * N);
    const float4 w0  = wr[lane +   0], w1  = wr[lane +  64], w2  = wr[lane + 128],
                 w3  = wr[lane + 192], w4  = wr[lane + 256], w5  = wr[lane + 320],
                 w6  = wr[lane + 384], w7  = wr[lane + 448], w8  = wr[lane + 512],
                 w9  = wr[lane + 576], w10 = wr[lane + 640], w11 = wr[lane + 704],
                 w12 = wr[lane + 768], w13 = wr[lane + 832], w14 = wr[lane + 896],
                 w15 = wr[lane + 960];

    // ---- init: ia buffer slot 0, and ZERO all flag slots (poison = 0xAA.. !)
    for (int i = wg * NTHR + tid; i < N; i += NBLK * NTHR)
        p.ia_buf[i] = p.ia0[i];
    if (tid == 0)
        __hip_atomic_store(&p.flags[wg * SLOT_STRIDE], 0u,
                           __ATOMIC_RELAXED, __HIP_MEMORY_SCOPE_AGENT);
    grid.sync();                          // init fully visible before first poll

    const float4* lds4 = (const float4*)ia_lds;
    float x = p.x_in[row];                // preloaded x for t=0

    for (int t = 0; t < T; ++t) {
        const float4* src = (const float4*)(p.ia_buf + (size_t)(t & 1) * N);
        float*        dst = p.ia_buf + (size_t)((t + 1) & 1) * N;

        // ---- stage I_add into LDS: 1024 float4 / 1024 threads
        ((float4*)ia_lds)[tid] = src[tid];
        __syncthreads();

        // ---- matvec from register-resident w
        float a = 0.f;
        { float4 q = lds4[lane +   0]; a += DOT(w0 , q); }
        { float4 q = lds4[lane +  64]; a += DOT(w1 , q); }
        { float4 q = lds4[lane + 128]; a += DOT(w2 , q); }
        { float4 q = lds4[lane + 192]; a += DOT(w3 , q); }
        { float4 q = lds4[lane + 256]; a += DOT(w4 , q); }
        { float4 q = lds4[lane + 320]; a += DOT(w5 , q); }
        { float4 q = lds4[lane + 384]; a += DOT(w6 , q); }
        { float4 q = lds4[lane + 448]; a += DOT(w7 , q); }
        { float4 q = lds4[lane + 512]; a += DOT(w8 , q); }
        { float4 q = lds4[lane + 576]; a += DOT(w9 , q); }
        { float4 q = lds4[lane + 640]; a += DOT(w10, q); }
        { float4 q = lds4[lane + 704]; a += DOT(w11, q); }
        { float4 q = lds4[lane + 768]; a += DOT(w12, q); }
        { float4 q = lds4[lane + 832]; a += DOT(w13, q); }
        { float4 q = lds4[lane + 896]; a += DOT(w14, q); }
        { float4 q = lds4[lane + 960]; a += DOT(w15, q); }

        #pragma unroll
        for (int m = 32; m >= 1; m >>= 1)
            a += __shfl_xor(a, m, 64);

        // ---- neuron update (uniform across the wave)
        float I      = x + a;
        float dv     = (I * c_RI - c_G * (v - c_EL)) / c_Cm;
        float v_next = v + dv;
        float thr    = ts + tv;
        float ssoft  = 1.f / (1.f + __expf(thr - v_next)); // sigmoid(v_next-thr)
        bool  sp     = (v_next >= thr);
        float v_reset = c_EL + c_fv * (v - c_EL) - c_dV;
        float v_new  = sp ? v_reset : v_next;
        float ts_new = (1.f - c_bs) * ts + (sp ? c_dts : 0.f);
        float dtv    = c_av * (v_new - c_EL) - c_bv * (tv - c_tinf);
        float tv_new = tv + (sp ? 0.f : dtv);
        float ia_new = (1.f - c_fI) * ia + ssoft * c_IA;

        v = v_new; ts = ts_new; tv = tv_new; ia = ia_new;

        if (lane == 0) {
            p.out[(size_t)t * N + row] = v_new;
            p.out[(size_t)T * N + (size_t)t * N + row] = ssoft;
            dst[row] = ia_new;
        }

        // ---- prefetch next x (latency hides under the barrier poll)
        if (t + 1 < T) x = p.x_in[(size_t)(t + 1) * N + row];

        // ---- distributed grid barrier: own-slot store, all-slot poll
        __syncthreads();                  // drains every wave's stores (vmcnt0)
        if (wave == 0) {
            const unsigned tgt = (unsigned)(t + 1);
            if (lane == 0) {
                __threadfence();          // publish all waves' dst/out stores
                __hip_atomic_store(&p.flags[wg * SLOT_STRIDE], tgt,
                                   __ATOMIC_RELAXED, __HIP_MEMORY_SCOPE_AGENT);
            }
            unsigned s0 = 0, s1 = 0, s2 = 0, s3 = 0;
            for (;;) {
                if (s0 < tgt) s0 = __hip_atomic_load(
                    &p.flags[(lane      ) * SLOT_STRIDE],
                    __ATOMIC_RELAXED, __HIP_MEMORY_SCOPE_AGENT);
                if (s1 < tgt) s1 = __hip_atomic_load(
                    &p.flags[(lane +  64) * SLOT_STRIDE],
                    __ATOMIC_RELAXED, __HIP_MEMORY_SCOPE_AGENT);
                if (s2 < tgt) s2 = __hip_atomic_load(
                    &p.flags[(lane + 128) * SLOT_STRIDE],
                    __ATOMIC_RELAXED, __HIP_MEMORY_SCOPE_AGENT);
                if (s3 < tgt) s3 = __hip_atomic_load(
                    &p.flags[(lane + 192) * SLOT_STRIDE],
                    __ATOMIC_RELAXED, __HIP_MEMORY_SCOPE_AGENT);
                bool done = (s0 >= tgt) & (s1 >= tgt) & (s2 >= tgt) & (s3 >= tgt);
                if (__all(done)) break;
                __builtin_amdgcn_s_sleep(1);
            }
            if (lane == 0) __threadfence();   // acquire: invalidate stale lines
        }
        __syncthreads();                  // release whole block; guards ia_lds
    }
}

extern "C" void kernel_launch(void* const* d_in, const int* in_sizes, int n_in,
                              void* d_out, int out_size, void* d_ws, size_t ws_size,
                              hipStream_t stream)
{
    Params p;
    p.x_in = (const float*)d_in[0];
    p.w    = (const float*)d_in[1];
    p.E_L  = (const float*)d_in[2];
    p.C_m  = (const float*)d_in[3];
    p.G    = (const float*)d_in[4];
    p.R_I  = (const float*)d_in[5];
    p.f_v  = (const float*)d_in[6];
    p.f_I  = (const float*)d_in[7];
    p.dts  = (const float*)d_in[8];
    p.b_s  = (const float*)d_in[9];
    p.a_v  = (const float*)d_in[10];
    p.b_v  = (const float*)d_in[11];
    p.tinf = (const float*)d_in[12];
    p.dV   = (const float*)d_in[13];
    p.I_A  = (const float*)d_in[14];
    p.v0   = (const float*)d_in[15];
    p.ts0  = (const float*)d_in[16];
    p.tv0  = (const float*)d_in[17];
    p.ia0  = (const float*)d_in[18];
    p.out  = (float*)d_out;
    p.flags  = (unsigned*)d_ws;                        // 256 * 64 B = 16 KB
    p.ia_buf = (float*)((char*)d_ws + 16 * 1024);      // 2*N*4 = 32 KB

    void* args[] = { &p };
    hipLaunchCooperativeKernel((const void*)glif_persistent,
                               dim3(NBLK), dim3(NTHR), args, 0, stream);
}

// Round 5
// 5904.408 us; speedup vs baseline: 14.3844x; 4.3232x over previous
//
#include <hip/hip_runtime.h>
#include <hip/hip_cooperative_groups.h>

namespace cg = cooperative_groups;

constexpr int N    = 4096;
constexpr int T    = 2048;
constexpr int NBLK = 256;                 // one WG per CU
constexpr int NTHR = 1024;                // 16 waves
constexpr int ROWS_PER_WG = N / NBLK;     // 16 -> 1 row per wave
constexpr int SLOT_STRIDE = 16;           // 16 uints = 64 B per flag slot

struct Params {
    const float *x_in, *w, *E_L, *C_m, *G, *R_I, *f_v, *f_I, *dts, *b_s,
                *a_v, *b_v, *tinf, *dV, *I_A, *v0, *ts0, *tv0, *ia0;
    float *out;          // [2, T, N]
    unsigned *flags;     // 256 slots x 64 B   (d_ws + 0)
    float *ia_buf;       // double buffer 2*N  (d_ws + 16 KB)
};

#define DOT(wv, iv) ((wv).x*(iv).x + (wv).y*(iv).y + (wv).z*(iv).z + (wv).w*(iv).w)

__global__ __launch_bounds__(NTHR, 4)
void glif_persistent(Params p)
{
    cg::grid_group grid = cg::this_grid();
    __shared__ float ia_lds[N];           // 16 KB

    const int tid  = threadIdx.x;
    const int wg   = blockIdx.x;
    const int wave = tid >> 6;
    const int lane = tid & 63;
    const int row  = wg * ROWS_PER_WG + wave;   // wave-uniform neuron index

    // ---- wave-uniform params (scalarized by compiler)
    const float c_EL = p.E_L[row],  c_Cm = p.C_m[row], c_G   = p.G[row];
    const float c_RI = p.R_I[row],  c_fv = p.f_v[row], c_fI  = p.f_I[row];
    const float c_dts = p.dts[row], c_bs = p.b_s[row], c_av  = p.a_v[row];
    const float c_bv  = p.b_v[row], c_tinf = p.tinf[row];
    const float c_dV  = p.dV[row],  c_IA = p.I_A[row];

    float v  = p.v0[row], ts = p.ts0[row], tv = p.tv0[row];
    float ia = p.ia0[row];                // this wave OWNS I_add[row]

    // ---- this wave's w row in 16 named float4 regs (AGPR/VGPR resident)
    const float4* wr = (const float4*)(p.w + (size_t)row * N);
    const float4 w0  = wr[lane +   0], w1  = wr[lane +  64], w2  = wr[lane + 128],
                 w3  = wr[lane + 192], w4  = wr[lane + 256], w5  = wr[lane + 320],
                 w6  = wr[lane + 384], w7  = wr[lane + 448], w8  = wr[lane + 512],
                 w9  = wr[lane + 576], w10 = wr[lane + 640], w11 = wr[lane + 704],
                 w12 = wr[lane + 768], w13 = wr[lane + 832], w14 = wr[lane + 896],
                 w15 = wr[lane + 960];

    // ---- init: ia buffer 0 (write-through so sc1 readers see it) + zero flags
    for (int i = wg * NTHR + tid; i < N; i += NBLK * NTHR)
        __hip_atomic_store(&p.ia_buf[i], p.ia0[i],
                           __ATOMIC_RELAXED, __HIP_MEMORY_SCOPE_AGENT);
    if (tid == 0)
        __hip_atomic_store(&p.flags[wg * SLOT_STRIDE], 0u,
                           __ATOMIC_RELAXED, __HIP_MEMORY_SCOPE_AGENT);
    grid.sync();                          // once per launch; publishes init

    const float4* lds4 = (const float4*)ia_lds;
    float x = p.x_in[row];                // preloaded x for t=0

    for (int t = 0; t < T; ++t) {
        const unsigned long long* src =
            (const unsigned long long*)(p.ia_buf + (size_t)(t & 1) * N);
        float* dst = p.ia_buf + (size_t)((t + 1) & 1) * N;

        // ---- stage I_add into LDS via L3-direct (sc1) loads: 2048 u64 total
        {
            unsigned long long q0 = __hip_atomic_load(
                src + tid, __ATOMIC_RELAXED, __HIP_MEMORY_SCOPE_AGENT);
            unsigned long long q1 = __hip_atomic_load(
                src + tid + NTHR, __ATOMIC_RELAXED, __HIP_MEMORY_SCOPE_AGENT);
            ((unsigned long long*)ia_lds)[tid]        = q0;
            ((unsigned long long*)ia_lds)[tid + NTHR] = q1;
        }
        __syncthreads();

        // ---- matvec from register-resident w
        float a = 0.f;
        { float4 q = lds4[lane +   0]; a += DOT(w0 , q); }
        { float4 q = lds4[lane +  64]; a += DOT(w1 , q); }
        { float4 q = lds4[lane + 128]; a += DOT(w2 , q); }
        { float4 q = lds4[lane + 192]; a += DOT(w3 , q); }
        { float4 q = lds4[lane + 256]; a += DOT(w4 , q); }
        { float4 q = lds4[lane + 320]; a += DOT(w5 , q); }
        { float4 q = lds4[lane + 384]; a += DOT(w6 , q); }
        { float4 q = lds4[lane + 448]; a += DOT(w7 , q); }
        { float4 q = lds4[lane + 512]; a += DOT(w8 , q); }
        { float4 q = lds4[lane + 576]; a += DOT(w9 , q); }
        { float4 q = lds4[lane + 640]; a += DOT(w10, q); }
        { float4 q = lds4[lane + 704]; a += DOT(w11, q); }
        { float4 q = lds4[lane + 768]; a += DOT(w12, q); }
        { float4 q = lds4[lane + 832]; a += DOT(w13, q); }
        { float4 q = lds4[lane + 896]; a += DOT(w14, q); }
        { float4 q = lds4[lane + 960]; a += DOT(w15, q); }

        #pragma unroll
        for (int m = 32; m >= 1; m >>= 1)
            a += __shfl_xor(a, m, 64);

        // ---- neuron update (uniform across the wave)
        float I      = x + a;
        float dv     = (I * c_RI - c_G * (v - c_EL)) / c_Cm;
        float v_next = v + dv;
        float thr    = ts + tv;
        float ssoft  = 1.f / (1.f + __expf(thr - v_next)); // sigmoid(v_next-thr)
        bool  sp     = (v_next >= thr);
        float v_reset = c_EL + c_fv * (v - c_EL) - c_dV;
        float v_new  = sp ? v_reset : v_next;
        float ts_new = (1.f - c_bs) * ts + (sp ? c_dts : 0.f);
        float dtv    = c_av * (v_new - c_EL) - c_bv * (tv - c_tinf);
        float tv_new = tv + (sp ? 0.f : dtv);
        float ia_new = (1.f - c_fI) * ia + ssoft * c_IA;

        v = v_new; ts = ts_new; tv = tv_new; ia = ia_new;

        if (lane == 0) {
            p.out[(size_t)t * N + row] = v_new;                 // cached, ok
            p.out[(size_t)T * N + (size_t)t * N + row] = ssoft; // cached, ok
            // publish I_add[row] write-through to L3 (no fence needed)
            __hip_atomic_store(&dst[row], ia_new,
                               __ATOMIC_RELAXED, __HIP_MEMORY_SCOPE_AGENT);
        }

        // ---- prefetch next x (latency hides under the barrier poll)
        if (t + 1 < T) x = p.x_in[(size_t)(t + 1) * N + row];

        // ---- fence-free distributed barrier:
        // syncthreads drains all waves' sc1 data stores (vmcnt0 before
        // s_barrier), so data is at L3 before the tag goes out.
        __syncthreads();
        if (wave == 0) {
            const unsigned tgt = (unsigned)(t + 1);
            if (lane == 0)
                __hip_atomic_store(&p.flags[wg * SLOT_STRIDE], tgt,
                                   __ATOMIC_RELAXED, __HIP_MEMORY_SCOPE_AGENT);
            unsigned s0 = 0, s1 = 0, s2 = 0, s3 = 0;
            for (;;) {
                if (s0 < tgt) s0 = __hip_atomic_load(
                    &p.flags[(lane      ) * SLOT_STRIDE],
                    __ATOMIC_RELAXED, __HIP_MEMORY_SCOPE_AGENT);
                if (s1 < tgt) s1 = __hip_atomic_load(
                    &p.flags[(lane +  64) * SLOT_STRIDE],
                    __ATOMIC_RELAXED, __HIP_MEMORY_SCOPE_AGENT);
                if (s2 < tgt) s2 = __hip_atomic_load(
                    &p.flags[(lane + 128) * SLOT_STRIDE],
                    __ATOMIC_RELAXED, __HIP_MEMORY_SCOPE_AGENT);
                if (s3 < tgt) s3 = __hip_atomic_load(
                    &p.flags[(lane + 192) * SLOT_STRIDE],
                    __ATOMIC_RELAXED, __HIP_MEMORY_SCOPE_AGENT);
                bool done = (s0 >= tgt) & (s1 >= tgt) & (s2 >= tgt) & (s3 >= tgt);
                if (__all(done)) break;
                __builtin_amdgcn_s_sleep(1);
            }
        }
        // release whole block; next-step sc1 loads are L3-direct, so no
        // cache invalidate is needed for them to see fresh data.
        __syncthreads();
    }
}

extern "C" void kernel_launch(void* const* d_in, const int* in_sizes, int n_in,
                              void* d_out, int out_size, void* d_ws, size_t ws_size,
                              hipStream_t stream)
{
    Params p;
    p.x_in = (const float*)d_in[0];
    p.w    = (const float*)d_in[1];
    p.E_L  = (const float*)d_in[2];
    p.C_m  = (const float*)d_in[3];
    p.G    = (const float*)d_in[4];
    p.R_I  = (const float*)d_in[5];
    p.f_v  = (const float*)d_in[6];
    p.f_I  = (const float*)d_in[7];
    p.dts  = (const float*)d_in[8];
    p.b_s  = (const float*)d_in[9];
    p.a_v  = (const float*)d_in[10];
    p.b_v  = (const float*)d_in[11];
    p.tinf = (const float*)d_in[12];
    p.dV   = (const float*)d_in[13];
    p.I_A  = (const float*)d_in[14];
    p.v0   = (const float*)d_in[15];
    p.ts0  = (const float*)d_in[16];
    p.tv0  = (const float*)d_in[17];
    p.ia0  = (const float*)d_in[18];
    p.out  = (float*)d_out;
    p.flags  = (unsigned*)d_ws;                        // 256 * 64 B = 16 KB
    p.ia_buf = (float*)((char*)d_ws + 16 * 1024);      // 2*N*4 = 32 KB

    void* args[] = { &p };
    hipLaunchCooperativeKernel((const void*)glif_persistent,
                               dim3(NBLK), dim3(NTHR), args, 0, stream);
}